// Round 9
// baseline (1734.383 us; speedup 1.0000x reference)
//
#include <hip/hip_runtime.h>
#include <math.h>

#define NC_   100000
#define ND_   100000
#define NN_   100000   // == NC_ == ND_
#define E_CNT 500000
#define L_CNT 100000
#define NH_   4
#define HD_   32
#define WCAT_SZ (129 * 384)

typedef __attribute__((ext_vector_type(8))) short short8;
typedef __attribute__((ext_vector_type(4))) float floatx4;

// fast tanh-gelu: tanh(z) = 1 - 2/(e^{2z}+1), e^x via HW v_exp, rcp via HW.
__device__ __forceinline__ float gelu_f(float x) {
    const float c0 = 0.7978845608028654f; // sqrt(2/pi)
    float z = c0 * (x + 0.044715f * x * x * x);
    float e = __expf(2.0f * z);
    float t = 1.0f - 2.0f * __builtin_amdgcn_rcpf(e + 1.0f);
    return 0.5f * x * (1.0f + t);
}

__device__ __forceinline__ unsigned short bf_rne(float x) {
    unsigned int u = __float_as_uint(x);
    u += 0x7fffu + ((u >> 16) & 1u);
    return (unsigned short)(u >> 16);
}
__device__ __forceinline__ float bf_to_f(unsigned short b) {
    return __uint_as_float(((unsigned int)b) << 16);
}

// truncation-based 3-term bf16 split: exact decomposition x = b0+b1+b2
__device__ __forceinline__ void split3t(const float* xv, short8* f) {
    #pragma unroll
    for (int i = 0; i < 8; i++) {
        unsigned int u0 = __float_as_uint(xv[i]);
        float r1 = xv[i] - __uint_as_float(u0 & 0xFFFF0000u);
        unsigned int u1 = __float_as_uint(r1);
        float r2 = r1 - __uint_as_float(u1 & 0xFFFF0000u);
        unsigned int u2 = __float_as_uint(r2);
        f[0][i] = (short)(u0 >> 16);
        f[1][i] = (short)(u1 >> 16);
        f[2][i] = (short)(u2 >> 16);
    }
}

// ======================= CSR build (both relations fused, grid.y = r) ==========
__global__ __launch_bounds__(256) void fill0_int(int* __restrict__ p, int n) {
    int i = blockIdx.x * 256 + threadIdx.x;
    if (i < n) p[i] = 0;
}

__global__ __launch_bounds__(256) void count_dst(const int* __restrict__ dstA,
                                                 const int* __restrict__ dstB,
                                                 int* __restrict__ cnt) {
    int r = blockIdx.y;
    const int* dst = r ? dstB : dstA;
    int e = blockIdx.x * 256 + threadIdx.x;
    if (e < E_CNT) atomicAdd(&cnt[r * NN_ + dst[e]], 1);
}

__global__ __launch_bounds__(256) void scan_a(const int* __restrict__ cnt,
                                              int* __restrict__ excl,
                                              int* __restrict__ partials) {
    __shared__ int sd[256];
    int r = blockIdx.y;
    cnt += r * NN_; excl += r * (NN_ + 1); partials += r * 128;
    int b = blockIdx.x, t = threadIdx.x;
    int base = b * 1024 + t * 4;
    int v0 = (base + 0 < NN_) ? cnt[base + 0] : 0;
    int v1 = (base + 1 < NN_) ? cnt[base + 1] : 0;
    int v2 = (base + 2 < NN_) ? cnt[base + 2] : 0;
    int v3 = (base + 3 < NN_) ? cnt[base + 3] : 0;
    int tsum = v0 + v1 + v2 + v3;
    sd[t] = tsum; __syncthreads();
    for (int off = 1; off < 256; off <<= 1) {
        int x = (t >= off) ? sd[t - off] : 0;
        __syncthreads();
        sd[t] += x;
        __syncthreads();
    }
    int excl_t = sd[t] - tsum;
    if (t == 255) partials[b] = sd[t];
    int q = excl_t;
    if (base + 0 < NN_) excl[base + 0] = q; q += v0;
    if (base + 1 < NN_) excl[base + 1] = q; q += v1;
    if (base + 2 < NN_) excl[base + 2] = q; q += v2;
    if (base + 3 < NN_) excl[base + 3] = q;
}

__global__ __launch_bounds__(128) void scan_b(int* __restrict__ partials) {
    __shared__ int sd[128];
    partials += blockIdx.x * 128;
    int t = threadIdx.x;
    int orig = (t < 98) ? partials[t] : 0;
    sd[t] = orig; __syncthreads();
    for (int off = 1; off < 128; off <<= 1) {
        int x = (t >= off) ? sd[t - off] : 0;
        __syncthreads();
        sd[t] += x;
        __syncthreads();
    }
    if (t < 98) partials[t] = sd[t] - orig;
}

__global__ __launch_bounds__(256) void scan_c(int* __restrict__ row_ptr,
                                              const int* __restrict__ partials,
                                              int* __restrict__ cursor) {
    int r = blockIdx.y;
    row_ptr += r * (NN_ + 1); partials += r * 128; cursor += r * NN_;
    int b = blockIdx.x, t = threadIdx.x;
    int base = b * 1024 + t * 4;
    int add = partials[b];
    #pragma unroll
    for (int j = 0; j < 4; j++) {
        int i = base + j;
        if (i < NN_) { int v = row_ptr[i] + add; row_ptr[i] = v; cursor[i] = v; }
    }
    if (b == 0 && t == 0) row_ptr[NN_] = E_CNT;
}

__global__ __launch_bounds__(256) void scatter_edges(const int* __restrict__ srcA,
                                                     const int* __restrict__ dstA,
                                                     const int* __restrict__ srcB,
                                                     const int* __restrict__ dstB,
                                                     int* __restrict__ cursor,
                                                     int* __restrict__ srcs) {
    int r = blockIdx.y;
    const int* src = r ? srcB : srcA;
    const int* dst = r ? dstB : dstA;
    cursor += r * NN_; srcs += r * E_CNT;
    int e = blockIdx.x * 256 + threadIdx.x;
    if (e >= E_CNT) return;
    int pos = atomicAdd(&cursor[dst[e]], 1);
    srcs[pos] = src[e];
}

// ======================= weight fusion (both layers in one launch) ==============
__global__ void fuse_weights(const float* __restrict__ qW, const float* __restrict__ qb,
                             const float* __restrict__ kW, const float* __restrict__ kb,
                             const float* __restrict__ vW, const float* __restrict__ vb,
                             const float* __restrict__ arel, const float* __restrict__ mrel,
                             float* __restrict__ WcatAll)
{
    int i  = blockIdx.x;   // 0..128 (128 == bias row)
    int t  = blockIdx.y;
    int lyr = blockIdx.z;
    int oc = threadIdx.x;  // 0..383
    int lt = lyr * 2 + t;
    float* Wcat = WcatAll + (size_t)lt * WCAT_SZ;
    float val;
    if (oc < 128) {
        val = (i < 128) ? qW[(size_t)(lt * 128 + i) * 128 + oc] : qb[lt * 128 + oc];
    } else {
        int which = (oc >= 256);
        int cc = oc - (which ? 256 : 128);
        int h = cc >> 5, e = cc & 31;
        const float* W = which ? vW : kW;
        const float* b = which ? vb : kb;
        const float* R = (which ? mrel : arel) + (size_t)(lt * NH_ + h) * HD_ * HD_ + e;
        float s = 0.f;
        if (i < 128) {
            const float* wrow = W + (size_t)(lt * 128 + i) * 128 + h * 32;
            #pragma unroll
            for (int d2 = 0; d2 < 32; d2++) s += wrow[d2] * R[d2 * 32];
        } else {
            const float* brow = b + lt * 128 + h * 32;
            #pragma unroll
            for (int d2 = 0; d2 < 32; d2++) s += brow[d2] * R[d2 * 32];
        }
        val = s;
    }
    Wcat[(size_t)((i < 128) ? i : 128) * 384 + oc] = val;
}

// ======================= weight 3-term bf16 pack (fragment-linear) =============
__global__ __launch_bounds__(256)
void pack_w(const float* __restrict__ W, int ldw, int matStride,
            unsigned short* __restrict__ out, int N, int outMatStride)
{
    int mat = blockIdx.y;
    int e = blockIdx.x * 256 + threadIdx.x;    // (nt*4 + s)*64 + lane
    int total = N * 16;                         // (N/16)*4*64
    if (e >= total) return;
    int lane = e & 63;
    int s = (e >> 6) & 3;
    int nt = e >> 8;
    int col = nt * 16 + (lane & 15);
    int k0 = s * 32 + ((lane >> 4) << 3);
    const float* src = W + (size_t)mat * matStride + (size_t)k0 * ldw + col;
    int ps = N * 128;
    unsigned short* o = out + (size_t)mat * outMatStride + (size_t)e * 8;
    short8 p0, p1, p2;
    #pragma unroll
    for (int j = 0; j < 8; j++) {
        float x = src[(size_t)j * ldw];
        unsigned short b0 = bf_rne(x);
        float x1 = x - bf_to_f(b0);
        unsigned short b1 = bf_rne(x1);
        float x2 = x1 - bf_to_f(b1);
        unsigned short b2 = bf_rne(x2);
        p0[j] = (short)b0; p1[j] = (short)b1; p2[j] = (short)b2;
    }
    *(short8*)(o)          = p0;
    *(short8*)(o + ps)     = p1;
    *(short8*)(o + 2 * ps) = p2;
}

// ======================= MFMA GEMM: slab loop, A split once per block ==========
// C[M,N] = A[M,128] @ B[128,N] + bias, fp32-grade accuracy from 6 bf16 MFMAs
// per fragment pair (3-term split, products >= 2^-16 kept, low->high order).
// Geometry: block = 128 rows (4 waves x 32) x nslab 64-col slabs. Per block:
// load + 3-term-split the A panel ONCE (af = 96 VGPR held across slabs), then
// per slab: {stage 48KB B slab -> LDS; 4 K-steps of pure ds_read_b128 + MFMA
// (no VALU); write C columns}. A is fetched once per launch instead of once
// per slab (FETCH / nslab). __launch_bounds__(256,3): VGPR cap 170 for the
// ~155 peak; 3 blocks/CU (48KB LDS) = 12 waves/CU. Numerics identical to R8.
// POST: C = relu(g*v + (1-g)*resid) (resid may alias C). Dual via ySplit.
template<int POST>
__global__ __launch_bounds__(256, 3)
void gemm_mfma(const float* __restrict__ A, int lda,
               const unsigned short* __restrict__ Bp, int pstride,
               const float* __restrict__ bias,
               float* __restrict__ C, int ldc, int M,
               const float* __restrict__ resid, const float* __restrict__ skipv,
               int ySplit, int nslab1,
               const float* __restrict__ A2, const unsigned short* __restrict__ Bp2,
               int pstride2, const float* __restrict__ bias2,
               float* __restrict__ C2, int ldc2, int nslab2)
{
    __shared__ unsigned short Blds[3 * 8192];   // 48 KB (one 64-col slab, 3 planes)
    int by = blockIdx.y;
    int nslab = nslab1;
    if (ySplit >= 0 && by >= ySplit) {
        A = A2; Bp = Bp2; pstride = pstride2; bias = bias2; C = C2; ldc = ldc2;
        nslab = nslab2;
        by -= ySplit;
    }
    int tid  = threadIdx.x;
    int wave = tid >> 6, lane = tid & 63;
    int quad = lane >> 4, l16 = lane & 15;
    int bm = blockIdx.x * 128;
    int bn0 = by * nslab * 64;

    int row0 = bm + wave * 32 + l16;
    // clamped rows: out-of-range rows read row M-1 (finite garbage, masked at store)
    int crow0 = min(row0, M - 1);
    int crow1 = min(row0 + 16, M - 1);
    const float* ap0 = A + (size_t)crow0 * lda + quad * 8;
    const float* ap1 = A + (size_t)crow1 * lda + quad * 8;

    // ---- load ENTIRE A panel (16 dwordx4) + slab-0 B (12 dwordx4): all in flight
    float4 ar[4][2][2];
    #pragma unroll
    for (int s = 0; s < 4; s++) {
        ar[s][0][0] = *(const float4*)(ap0 + s * 32);
        ar[s][0][1] = *(const float4*)(ap0 + s * 32 + 4);
        ar[s][1][0] = *(const float4*)(ap1 + s * 32);
        ar[s][1][1] = *(const float4*)(ap1 + s * 32 + 4);
    }
    const unsigned short* slab0 = Bp + (size_t)bn0 * 128;
    uint4 breg[12];
    #pragma unroll
    for (int p = 0; p < 3; p++)
        #pragma unroll
        for (int i = 0; i < 4; i++)
            breg[p * 4 + i] = ((const uint4*)(slab0 + (size_t)p * pstride))[i * 256 + tid];
    __builtin_amdgcn_sched_barrier(0);

    // ---- split A panel once (overlaps B-load latency); ar dies here
    short8 af[2][4][3];
    #pragma unroll
    for (int s = 0; s < 4; s++) {
        #pragma unroll
        for (int m = 0; m < 2; m++) {
            float xv[8];
            *(float4*)&xv[0] = ar[s][m][0];
            *(float4*)&xv[4] = ar[s][m][1];
            split3t(xv, af[m][s]);
        }
    }

    float g = 0.f, omg = 0.f;
    if (POST) { float sv = skipv[0]; g = 1.0f / (1.0f + expf(-sv)); omg = 1.0f - g; }

    constexpr int PA[6] = {0, 1, 2, 0, 1, 0};   // product order: low -> high
    constexpr int PB[6] = {2, 1, 0, 1, 0, 0};

    for (int j = 0; j < nslab; j++) {
        if (j > 0) {
            __syncthreads();   // all waves done reading previous slab
            const unsigned short* slab = Bp + (size_t)(bn0 + j * 64) * 128;
            #pragma unroll
            for (int p = 0; p < 3; p++)
                #pragma unroll
                for (int i = 0; i < 4; i++)
                    breg[p * 4 + i] = ((const uint4*)(slab + (size_t)p * pstride))[i * 256 + tid];
        }
        // ---- write staged slab to LDS
        #pragma unroll
        for (int p = 0; p < 3; p++)
            #pragma unroll
            for (int i = 0; i < 4; i++)
                ((uint4*)&Blds[p * 8192])[i * 256 + tid] = breg[p * 4 + i];
        __syncthreads();

        floatx4 acc[2][4];
        #pragma unroll
        for (int m = 0; m < 2; m++)
            #pragma unroll
            for (int ct = 0; ct < 4; ct++) acc[m][ct] = (floatx4){0.f, 0.f, 0.f, 0.f};

        // ---- 4 K-steps: pure {12x ds_read_b128 + 48 MFMA}, zero VALU
        #pragma unroll
        for (int s = 0; s < 4; s++) {
            short8 bfr[4][3];
            #pragma unroll
            for (int ct = 0; ct < 4; ct++)
                #pragma unroll
                for (int p = 0; p < 3; p++)
                    bfr[ct][p] = *(const short8*)&Blds[p * 8192 + ct * 2048 + s * 512 + lane * 8];
            #pragma unroll
            for (int o = 0; o < 6; o++) {
                #pragma unroll
                for (int ct = 0; ct < 4; ct++) {
                    acc[0][ct] = __builtin_amdgcn_mfma_f32_16x16x32_bf16(
                        af[0][s][PA[o]], bfr[ct][PB[o]], acc[0][ct], 0, 0, 0);
                    acc[1][ct] = __builtin_amdgcn_mfma_f32_16x16x32_bf16(
                        af[1][s][PA[o]], bfr[ct][PB[o]], acc[1][ct], 0, 0, 0);
                }
            }
        }

        // ---- epilogue for slab j: C/D layout col=lane&15, row=quad*4+reg
        #pragma unroll
        for (int m = 0; m < 2; m++) {
            #pragma unroll
            for (int ct = 0; ct < 4; ct++) {
                int col = bn0 + j * 64 + ct * 16 + l16;
                float bv = bias[col];
                #pragma unroll
                for (int i = 0; i < 4; i++) {
                    int r = bm + wave * 32 + m * 16 + quad * 4 + i;
                    if (r < M) {
                        float v = acc[m][ct][i] + bv;
                        if (POST) {
                            float rr = resid[(size_t)r * ldc + col];
                            v = fmaxf(g * v + omg * rr, 0.f);
                        }
                        C[(size_t)r * ldc + col] = v;
                    }
                }
            }
        }
    }
}

// ======================= fused attention gather (4 edges in flight) ============
// One wave per dst node, 16 lanes/edge, 4 edges in flight; distributed gelu.
__global__ __launch_bounds__(256)
void attn_gather(const int* __restrict__ row_ptr, const int* __restrict__ srcs,
                 float* __restrict__ qo, const float* __restrict__ kv,
                 const float* __restrict__ prel, int ndst)
{
    int wave = (blockIdx.x * 256 + threadIdx.x) >> 6;
    int lane = threadIdx.x & 63;
    if (wave >= ndst) return;
    int d = wave;
    int gl = lane & 15;
    int group = lane >> 4;
    int h = gl >> 2;
    float pr = prel[h] * 0.17677669529663687f;  // prel / sqrt(32)
    int beg = row_ptr[d], end = row_ptr[d + 1];
    const float* qrow = qo + (size_t)d * 128 + gl * 8;
    float4 q0 = *(const float4*)(qrow);
    float4 q1 = *(const float4*)(qrow + 4);
    float m = -1.0e30f, l = 0.f;
    float4 acc0 = make_float4(0.f,0.f,0.f,0.f), acc1 = acc0;
    int nt = (end - beg + 3) >> 2;
    for (int t = 0; t < nt; t++) {
        int i = beg + (t << 2) + group;
        if (i < end) {
            int s = srcs[i];
            const float* row = kv + (size_t)s * 256 + gl * 8;
            float4 k0 = *(const float4*)(row);
            float4 k1 = *(const float4*)(row + 4);
            float4 v0 = *(const float4*)(row + 128);
            float4 v1 = *(const float4*)(row + 132);
            float part = q0.x*k0.x + q0.y*k0.y + q0.z*k0.z + q0.w*k0.w
                       + q1.x*k1.x + q1.y*k1.y + q1.z*k1.z + q1.w*k1.w;
            part += __shfl_xor(part, 1);
            part += __shfl_xor(part, 2);
            float a = part * pr;
            float mn = fmaxf(m, a);
            float scale = __expf(m - mn);
            float p = __expf(a - mn);
            l = l * scale + p;
            acc0.x = acc0.x * scale + p * v0.x;
            acc0.y = acc0.y * scale + p * v0.y;
            acc0.z = acc0.z * scale + p * v0.z;
            acc0.w = acc0.w * scale + p * v0.w;
            acc1.x = acc1.x * scale + p * v1.x;
            acc1.y = acc1.y * scale + p * v1.y;
            acc1.z = acc1.z * scale + p * v1.z;
            acc1.w = acc1.w * scale + p * v1.w;
            m = mn;
        }
    }
    #pragma unroll
    for (int mask = 16; mask <= 32; mask <<= 1) {
        float m_o = __shfl_xor(m, mask);
        float l_o = __shfl_xor(l, mask);
        float4 a0o, a1o;
        a0o.x = __shfl_xor(acc0.x, mask); a0o.y = __shfl_xor(acc0.y, mask);
        a0o.z = __shfl_xor(acc0.z, mask); a0o.w = __shfl_xor(acc0.w, mask);
        a1o.x = __shfl_xor(acc1.x, mask); a1o.y = __shfl_xor(acc1.y, mask);
        a1o.z = __shfl_xor(acc1.z, mask); a1o.w = __shfl_xor(acc1.w, mask);
        float mn = fmaxf(m, m_o);
        float s0 = __expf(m - mn), s1 = __expf(m_o - mn);
        l = l * s0 + l_o * s1;
        acc0.x = acc0.x * s0 + a0o.x * s1; acc0.y = acc0.y * s0 + a0o.y * s1;
        acc0.z = acc0.z * s0 + a0o.z * s1; acc0.w = acc0.w * s0 + a0o.w * s1;
        acc1.x = acc1.x * s0 + a1o.x * s1; acc1.y = acc1.y * s0 + a1o.y * s1;
        acc1.z = acc1.z * s0 + a1o.z * s1; acc1.w = acc1.w * s0 + a1o.w * s1;
        m = mn;
    }
    float inv = (beg == end) ? 0.f : __builtin_amdgcn_rcpf(l + 1e-16f);
    // distributed gelu + store: group g handles floats [2g, 2g+2) of its column
    float s0v, s1v;
    if (group == 0)      { s0v = acc0.x; s1v = acc0.y; }
    else if (group == 1) { s0v = acc0.z; s1v = acc0.w; }
    else if (group == 2) { s0v = acc1.x; s1v = acc1.y; }
    else                 { s0v = acc1.z; s1v = acc1.w; }
    float2 o;
    o.x = gelu_f(s0v * inv);
    o.y = gelu_f(s1v * inv);
    *(float2*)(qo + (size_t)d * 128 + gl * 8 + group * 2) = o;
}

// ======================= final scoring =======================
__global__ __launch_bounds__(256)
void score_pairs(const int* __restrict__ ic, const int* __restrict__ id,
                 const float* __restrict__ zC, const float* __restrict__ zD,
                 float* __restrict__ out)
{
    int gid = blockIdx.x * 256 + threadIdx.x;
    int p = gid >> 4, lane = gid & 15;
    if (p >= L_CNT) return;
    int c = ic[p], d = id[p];
    float4 a = *(const float4*)(zC + (size_t)c * 64 + lane * 4);
    float4 b = *(const float4*)(zD + (size_t)d * 64 + lane * 4);
    float s = a.x * b.x + a.y * b.y + a.z * b.z + a.w * b.w;
    s += __shfl_down(s, 8, 16);
    s += __shfl_down(s, 4, 16);
    s += __shfl_down(s, 2, 16);
    s += __shfl_down(s, 1, 16);
    if (lane == 0) out[p] = fminf(10.0f, fmaxf(-10.0f, s));
}

extern "C" void kernel_launch(void* const* d_in, const int* in_sizes, int n_in,
                              void* d_out, int out_size, void* d_ws, size_t ws_size,
                              hipStream_t stream)
{
    float* xC = (float*)d_in[0];
    float* xD = (float*)d_in[1];
    const float* kW   = (const float*)d_in[2];
    const float* kb   = (const float*)d_in[3];
    const float* qW   = (const float*)d_in[4];
    const float* qb   = (const float*)d_in[5];
    const float* vW   = (const float*)d_in[6];
    const float* vb   = (const float*)d_in[7];
    const float* aW   = (const float*)d_in[8];
    const float* ab   = (const float*)d_in[9];
    const float* skip = (const float*)d_in[10];
    const float* arel = (const float*)d_in[11];
    const float* mrel = (const float*)d_in[12];
    const float* prel = (const float*)d_in[13];
    const float* outW = (const float*)d_in[14];
    const float* outb = (const float*)d_in[15];
    const int* ei_cd  = (const int*)d_in[16];
    const int* ei_dc  = (const int*)d_in[17];
    const int* eli    = (const int*)d_in[18];

    // ---- workspace ≈ 163 MB ----
    float* ws = (float*)d_ws;
    size_t off = 0;
    float* kv    = ws + off; off += (size_t)NN_ * 256;   // src [k|v]
    float* qo    = ws + off; off += (size_t)NN_ * 128;   // dst q -> gelu(attn out)
    float* Wcat  = ws + off; off += (size_t)4 * WCAT_SZ;
    unsigned short* WsCat = (unsigned short*)(ws + off); off += (4 * 3 * 384 * 128) / 2;
    unsigned short* aWs   = (unsigned short*)(ws + off); off += (4 * 3 * 128 * 128) / 2;
    unsigned short* outWs = (unsigned short*)(ws + off); off += (2 * 3 * 64 * 128) / 2;
    int* iws = (int*)(ws + off);
    size_t ioff = 0;
    int* rp      = iws + ioff; ioff += 2 * (NN_ + 1);
    int* srcsA   = iws + ioff; ioff += 2 * E_CNT;
    int* cnt     = iws + ioff; ioff += 2 * NN_;
    int* cursor  = iws + ioff; ioff += 2 * NN_;
    int* partial = iws + ioff; ioff += 256;
    float* zC = kv;
    float* zD = kv + (size_t)NN_ * 128;

    const int gridM = (NN_ + 127) / 128;          // 782 (128-row blocks)
    const int gE    = (E_CNT + 255) / 256;
    const int gN2   = (2 * NN_ + 255) / 256;
    const int gScan = 98;
    const int gGath = (NN_ + 3) / 4;

    // ---- CSR for both relations ----
    fill0_int<<<gN2, 256, 0, stream>>>(cnt, 2 * NN_);
    count_dst<<<dim3(gE, 2), 256, 0, stream>>>(ei_cd + E_CNT, ei_dc + E_CNT, cnt);
    scan_a<<<dim3(gScan, 2), 256, 0, stream>>>(cnt, rp, partial);
    scan_b<<<2, 128, 0, stream>>>(partial);
    scan_c<<<dim3(gScan, 2), 256, 0, stream>>>(rp, partial, cursor);
    scatter_edges<<<dim3(gE, 2), 256, 0, stream>>>(ei_cd, ei_cd + E_CNT,
                                                   ei_dc, ei_dc + E_CNT, cursor, srcsA);
    int* rp_cd   = rp;
    int* rp_dc   = rp + (NN_ + 1);
    int* srcs_cd = srcsA;
    int* srcs_dc = srcsA + E_CNT;

    // ---- weight fusion + bf16 3-term fragment-linear packs ----
    fuse_weights<<<dim3(129, 2, 2), 384, 0, stream>>>(qW, qb, kW, kb, vW, vb,
                                                      arel, mrel, Wcat);
    pack_w<<<dim3((384 * 16 + 255) / 256, 4), 256, 0, stream>>>(
        Wcat, 384, WCAT_SZ, WsCat, 384, 3 * 384 * 128);
    pack_w<<<dim3((128 * 16 + 255) / 256, 4), 256, 0, stream>>>(
        aW, 128, 128 * 128, aWs, 128, 3 * 128 * 128);
    pack_w<<<dim3((64 * 16 + 255) / 256, 2), 256, 0, stream>>>(
        outW, 64, 128 * 64, outWs, 64, 3 * 64 * 128);

    const int PS_CAT = 384 * 128;   // plane strides
    const int PS_AW  = 128 * 128;
    const int PS_OW  = 64 * 128;

    for (int l = 0; l < 2; l++) {
        const float* abl = ab + (size_t)l * 2 * 128;
        float* WcC = Wcat + (size_t)(l * 2 + 0) * WCAT_SZ;
        float* WcD = Wcat + (size_t)(l * 2 + 1) * WCAT_SZ;
        const unsigned short* WsC = WsCat + (size_t)(l * 2 + 0) * 3 * PS_CAT;
        const unsigned short* WsD = WsCat + (size_t)(l * 2 + 1) * 3 * PS_CAT;
        const unsigned short* aWsD = aWs + (size_t)(l * 2 + 1) * 3 * PS_AW;
        const unsigned short* aWsC = aWs + (size_t)(l * 2 + 0) * 3 * PS_AW;

        // ---- relation 0: C -> D ----  dual: y0 kvC (4-slab loop), y1 qD (2-slab)
        gemm_mfma<0><<<dim3(gridM, 2), 256, 0, stream>>>(
            xC, 128, WsC + 128 * 128, PS_CAT, WcC + 128 * 384 + 128, kv, 256, NC_,
            nullptr, nullptr,
            1, 4, xD, WsD, PS_CAT, WcD + 128 * 384, qo, 128, 2);
        attn_gather<<<gGath, 256, 0, stream>>>(rp_cd, srcs_cd, qo, kv,
                                               prel + (l * 2 + 0) * 4, ND_);

        // kvD from OLD xD (4-slab loop)
        gemm_mfma<0><<<dim3(gridM, 1), 256, 0, stream>>>(
            xD, 128, WsD + 128 * 128, PS_CAT, WcD + 128 * 384 + 128, kv, 256, ND_,
            nullptr, nullptr, -1, 4, nullptr, nullptr, 0, nullptr, nullptr, 0, 0);

        // epilogue D (2-slab loop)
        gemm_mfma<1><<<dim3(gridM, 1), 256, 0, stream>>>(
            qo, 128, aWsD, PS_AW, abl + 128, xD, 128, ND_,
            xD, skip + l * 2 + 1, -1, 2, nullptr, nullptr, 0, nullptr, nullptr, 0, 0);

        // ---- relation 1: D -> C ---- qC (2-slab loop)
        gemm_mfma<0><<<dim3(gridM, 1), 256, 0, stream>>>(
            xC, 128, WsC, PS_CAT, WcC + 128 * 384, qo, 128, NC_,
            nullptr, nullptr, -1, 2, nullptr, nullptr, 0, nullptr, nullptr, 0, 0);
        attn_gather<<<gGath, 256, 0, stream>>>(rp_dc, srcs_dc, qo, kv,
                                               prel + (l * 2 + 1) * 4, NC_);

        // epilogue C (2-slab loop)
        gemm_mfma<1><<<dim3(gridM, 1), 256, 0, stream>>>(
            qo, 128, aWsC, PS_AW, abl, xC, 128, NC_,
            xC, skip + l * 2 + 0, -1, 2, nullptr, nullptr, 0, nullptr, nullptr, 0, 0);
    }

    // final projections z = x @ outW + outb, both types dual (1 slab each)
    gemm_mfma<0><<<dim3(gridM, 2), 256, 0, stream>>>(
        xC, 128, outWs, PS_OW, outb, zC, 64, NC_, nullptr, nullptr,
        1, 1, xD, outWs + 3 * PS_OW, PS_OW, outb + 64, zD, 64, 1);

    score_pairs<<<(L_CNT * 16 + 255) / 256, 256, 0, stream>>>(
        eli, eli + L_CNT, zC, zD, (float*)d_out);
}

// Round 10
// 1161.592 us; speedup vs baseline: 1.4931x; 1.4931x over previous
//
#include <hip/hip_runtime.h>
#include <math.h>

#define NC_   100000
#define ND_   100000
#define NN_   100000   // == NC_ == ND_
#define E_CNT 500000
#define L_CNT 100000
#define NH_   4
#define HD_   32
#define WCAT_SZ (129 * 384)

typedef __attribute__((ext_vector_type(8))) short short8;
typedef __attribute__((ext_vector_type(4))) float floatx4;

// fast tanh-gelu: tanh(z) = 1 - 2/(e^{2z}+1), e^x via HW v_exp, rcp via HW.
__device__ __forceinline__ float gelu_f(float x) {
    const float c0 = 0.7978845608028654f; // sqrt(2/pi)
    float z = c0 * (x + 0.044715f * x * x * x);
    float e = __expf(2.0f * z);
    float t = 1.0f - 2.0f * __builtin_amdgcn_rcpf(e + 1.0f);
    return 0.5f * x * (1.0f + t);
}

__device__ __forceinline__ unsigned short bf_rne(float x) {
    unsigned int u = __float_as_uint(x);
    u += 0x7fffu + ((u >> 16) & 1u);
    return (unsigned short)(u >> 16);
}
__device__ __forceinline__ float bf_to_f(unsigned short b) {
    return __uint_as_float(((unsigned int)b) << 16);
}

// truncation-based 3-term bf16 split: exact decomposition x = b0+b1+b2
__device__ __forceinline__ void split3t(const float* xv, short8* f) {
    #pragma unroll
    for (int i = 0; i < 8; i++) {
        unsigned int u0 = __float_as_uint(xv[i]);
        float r1 = xv[i] - __uint_as_float(u0 & 0xFFFF0000u);
        unsigned int u1 = __float_as_uint(r1);
        float r2 = r1 - __uint_as_float(u1 & 0xFFFF0000u);
        unsigned int u2 = __float_as_uint(r2);
        f[0][i] = (short)(u0 >> 16);
        f[1][i] = (short)(u1 >> 16);
        f[2][i] = (short)(u2 >> 16);
    }
}

// ======================= CSR build (both relations fused, grid.y = r) ==========
__global__ __launch_bounds__(256) void fill0_int(int* __restrict__ p, int n) {
    int i = blockIdx.x * 256 + threadIdx.x;
    if (i < n) p[i] = 0;
}

__global__ __launch_bounds__(256) void count_dst(const int* __restrict__ dstA,
                                                 const int* __restrict__ dstB,
                                                 int* __restrict__ cnt) {
    int r = blockIdx.y;
    const int* dst = r ? dstB : dstA;
    int e = blockIdx.x * 256 + threadIdx.x;
    if (e < E_CNT) atomicAdd(&cnt[r * NN_ + dst[e]], 1);
}

__global__ __launch_bounds__(256) void scan_a(const int* __restrict__ cnt,
                                              int* __restrict__ excl,
                                              int* __restrict__ partials) {
    __shared__ int sd[256];
    int r = blockIdx.y;
    cnt += r * NN_; excl += r * (NN_ + 1); partials += r * 128;
    int b = blockIdx.x, t = threadIdx.x;
    int base = b * 1024 + t * 4;
    int v0 = (base + 0 < NN_) ? cnt[base + 0] : 0;
    int v1 = (base + 1 < NN_) ? cnt[base + 1] : 0;
    int v2 = (base + 2 < NN_) ? cnt[base + 2] : 0;
    int v3 = (base + 3 < NN_) ? cnt[base + 3] : 0;
    int tsum = v0 + v1 + v2 + v3;
    sd[t] = tsum; __syncthreads();
    for (int off = 1; off < 256; off <<= 1) {
        int x = (t >= off) ? sd[t - off] : 0;
        __syncthreads();
        sd[t] += x;
        __syncthreads();
    }
    int excl_t = sd[t] - tsum;
    if (t == 255) partials[b] = sd[t];
    int q = excl_t;
    if (base + 0 < NN_) excl[base + 0] = q; q += v0;
    if (base + 1 < NN_) excl[base + 1] = q; q += v1;
    if (base + 2 < NN_) excl[base + 2] = q; q += v2;
    if (base + 3 < NN_) excl[base + 3] = q;
}

__global__ __launch_bounds__(128) void scan_b(int* __restrict__ partials) {
    __shared__ int sd[128];
    partials += blockIdx.x * 128;
    int t = threadIdx.x;
    int orig = (t < 98) ? partials[t] : 0;
    sd[t] = orig; __syncthreads();
    for (int off = 1; off < 128; off <<= 1) {
        int x = (t >= off) ? sd[t - off] : 0;
        __syncthreads();
        sd[t] += x;
        __syncthreads();
    }
    if (t < 98) partials[t] = sd[t] - orig;
}

__global__ __launch_bounds__(256) void scan_c(int* __restrict__ row_ptr,
                                              const int* __restrict__ partials,
                                              int* __restrict__ cursor) {
    int r = blockIdx.y;
    row_ptr += r * (NN_ + 1); partials += r * 128; cursor += r * NN_;
    int b = blockIdx.x, t = threadIdx.x;
    int base = b * 1024 + t * 4;
    int add = partials[b];
    #pragma unroll
    for (int j = 0; j < 4; j++) {
        int i = base + j;
        if (i < NN_) { int v = row_ptr[i] + add; row_ptr[i] = v; cursor[i] = v; }
    }
    if (b == 0 && t == 0) row_ptr[NN_] = E_CNT;
}

__global__ __launch_bounds__(256) void scatter_edges(const int* __restrict__ srcA,
                                                     const int* __restrict__ dstA,
                                                     const int* __restrict__ srcB,
                                                     const int* __restrict__ dstB,
                                                     int* __restrict__ cursor,
                                                     int* __restrict__ srcs) {
    int r = blockIdx.y;
    const int* src = r ? srcB : srcA;
    const int* dst = r ? dstB : dstA;
    cursor += r * NN_; srcs += r * E_CNT;
    int e = blockIdx.x * 256 + threadIdx.x;
    if (e >= E_CNT) return;
    int pos = atomicAdd(&cursor[dst[e]], 1);
    srcs[pos] = src[e];
}

// ======================= weight fusion (both layers in one launch) ==============
__global__ void fuse_weights(const float* __restrict__ qW, const float* __restrict__ qb,
                             const float* __restrict__ kW, const float* __restrict__ kb,
                             const float* __restrict__ vW, const float* __restrict__ vb,
                             const float* __restrict__ arel, const float* __restrict__ mrel,
                             float* __restrict__ WcatAll)
{
    int i  = blockIdx.x;   // 0..128 (128 == bias row)
    int t  = blockIdx.y;
    int lyr = blockIdx.z;
    int oc = threadIdx.x;  // 0..383
    int lt = lyr * 2 + t;
    float* Wcat = WcatAll + (size_t)lt * WCAT_SZ;
    float val;
    if (oc < 128) {
        val = (i < 128) ? qW[(size_t)(lt * 128 + i) * 128 + oc] : qb[lt * 128 + oc];
    } else {
        int which = (oc >= 256);
        int cc = oc - (which ? 256 : 128);
        int h = cc >> 5, e = cc & 31;
        const float* W = which ? vW : kW;
        const float* b = which ? vb : kb;
        const float* R = (which ? mrel : arel) + (size_t)(lt * NH_ + h) * HD_ * HD_ + e;
        float s = 0.f;
        if (i < 128) {
            const float* wrow = W + (size_t)(lt * 128 + i) * 128 + h * 32;
            #pragma unroll
            for (int d2 = 0; d2 < 32; d2++) s += wrow[d2] * R[d2 * 32];
        } else {
            const float* brow = b + lt * 128 + h * 32;
            #pragma unroll
            for (int d2 = 0; d2 < 32; d2++) s += brow[d2] * R[d2 * 32];
        }
        val = s;
    }
    Wcat[(size_t)((i < 128) ? i : 128) * 384 + oc] = val;
}

// ======================= weight 3-term bf16 pack (fragment-linear) =============
__global__ __launch_bounds__(256)
void pack_w(const float* __restrict__ W, int ldw, int matStride,
            unsigned short* __restrict__ out, int N, int outMatStride)
{
    int mat = blockIdx.y;
    int e = blockIdx.x * 256 + threadIdx.x;    // (nt*4 + s)*64 + lane
    int total = N * 16;                         // (N/16)*4*64
    if (e >= total) return;
    int lane = e & 63;
    int s = (e >> 6) & 3;
    int nt = e >> 8;
    int col = nt * 16 + (lane & 15);
    int k0 = s * 32 + ((lane >> 4) << 3);
    const float* src = W + (size_t)mat * matStride + (size_t)k0 * ldw + col;
    int ps = N * 128;
    unsigned short* o = out + (size_t)mat * outMatStride + (size_t)e * 8;
    short8 p0, p1, p2;
    #pragma unroll
    for (int j = 0; j < 8; j++) {
        float x = src[(size_t)j * ldw];
        unsigned short b0 = bf_rne(x);
        float x1 = x - bf_to_f(b0);
        unsigned short b1 = bf_rne(x1);
        float x2 = x1 - bf_to_f(b1);
        unsigned short b2 = bf_rne(x2);
        p0[j] = (short)b0; p1[j] = (short)b1; p2[j] = (short)b2;
    }
    *(short8*)(o)          = p0;
    *(short8*)(o + ps)     = p1;
    *(short8*)(o + 2 * ps) = p2;
}

// ======================= MFMA GEMM: B slab in LDS, 8-wave blocks ===============
// R8 structure (best verified) + XCD-chunk swizzle: remap (bx,by) so all
// y-slabs of one 256-row panel get contiguous wgids on ONE XCD -> the A panel
// is fetched into 1 L2 instead of gridDim.y of them. Bijective for any nwg.
template<int POST>
__global__ __launch_bounds__(512, 4)
void gemm_mfma(const float* __restrict__ A, int lda,
               const unsigned short* __restrict__ Bp, int pstride,
               const float* __restrict__ bias,
               float* __restrict__ C, int ldc, int M,
               const float* __restrict__ resid, const float* __restrict__ skipv,
               int ySplit,
               const float* __restrict__ A2, const unsigned short* __restrict__ Bp2,
               int pstride2, const float* __restrict__ bias2,
               float* __restrict__ C2, int ldc2)
{
    __shared__ unsigned short Blds[3 * 8192];   // 48 KB
    // ---- XCD-chunk swizzle (assumes flat%8 round-robin; harmless otherwise)
    int nwg  = gridDim.x * gridDim.y;
    int flat = blockIdx.y * gridDim.x + blockIdx.x;
    int xcd = flat & 7, gseq = flat >> 3;
    int q8 = nwg >> 3, r8 = nwg & 7;
    int wgid = (xcd < r8 ? xcd * (q8 + 1) : r8 * (q8 + 1) + (xcd - r8) * q8) + gseq;
    int ny = gridDim.y;
    int by = wgid % ny;            // slab-fastest: panel's slabs adjacent
    int bx = wgid / ny;

    if (ySplit >= 0 && by >= ySplit) {
        A = A2; Bp = Bp2; pstride = pstride2; bias = bias2; C = C2; ldc = ldc2;
        by -= ySplit;
    }
    int tid  = threadIdx.x;
    int wave = tid >> 6, lane = tid & 63;
    int quad = lane >> 4, l16 = lane & 15;
    int bm = bx * 256;
    int bn = by * 64;

    // ---- stage the 64-col B slab (3 planes x 8192 elem) into LDS, once
    {
        const unsigned short* slab = Bp + (size_t)(bn >> 4) * 2048;
        #pragma unroll
        for (int p = 0; p < 3; p++) {
            const uint4* src = (const uint4*)(slab + (size_t)p * pstride);
            uint4* dst = (uint4*)&Blds[p * 8192];
            #pragma unroll
            for (int i = 0; i < 2; i++) dst[i * 512 + tid] = src[i * 512 + tid];
        }
    }

    int row0 = bm + wave * 32 + l16;
    // clamped rows: out-of-range rows read row M-1 (finite garbage, masked at store)
    int crow0 = min(row0, M - 1);
    int crow1 = min(row0 + 16, M - 1);
    const float* ap0 = A + (size_t)crow0 * lda + quad * 8;
    const float* ap1 = A + (size_t)crow1 * lda + quad * 8;

    // A ping-pong: load step 0 now
    float4 ar[2][2][2];
    ar[0][0][0] = *(const float4*)(ap0);
    ar[0][0][1] = *(const float4*)(ap0 + 4);
    ar[0][1][0] = *(const float4*)(ap1);
    ar[0][1][1] = *(const float4*)(ap1 + 4);

    floatx4 acc[2][4];
    #pragma unroll
    for (int m = 0; m < 2; m++)
        #pragma unroll
        for (int ct = 0; ct < 4; ct++) acc[m][ct] = (floatx4){0.f, 0.f, 0.f, 0.f};

    __syncthreads();

    constexpr int PA[6] = {0, 1, 2, 0, 1, 0};   // product order: low -> high
    constexpr int PB[6] = {2, 1, 0, 1, 0, 0};

    #pragma unroll
    for (int s = 0; s < 4; s++) {
        const int cur = s & 1, nxt = cur ^ 1;
        if (s < 3) {  // compile-time after unroll: prefetch A for step s+1
            ar[nxt][0][0] = *(const float4*)(ap0 + (s + 1) * 32);
            ar[nxt][0][1] = *(const float4*)(ap0 + (s + 1) * 32 + 4);
            ar[nxt][1][0] = *(const float4*)(ap1 + (s + 1) * 32);
            ar[nxt][1][1] = *(const float4*)(ap1 + (s + 1) * 32 + 4);
        }
        __builtin_amdgcn_sched_barrier(0);   // pin prefetch issue before compute
        // ---- B fragments from LDS (12x ds_read_b128, lane-linear: conflict-free)
        short8 bfr[4][3];
        #pragma unroll
        for (int ct = 0; ct < 4; ct++)
            #pragma unroll
            for (int p = 0; p < 3; p++)
                bfr[ct][p] = *(const short8*)&Blds[p * 8192 + ct * 2048 + s * 512 + lane * 8];
        // ---- split current A (cheap truncation split; overlaps ds_read latency)
        short8 af0[3], af1[3];
        {
            float xv[8];
            *(float4*)&xv[0] = ar[cur][0][0]; *(float4*)&xv[4] = ar[cur][0][1];
            split3t(xv, af0);
        }
        {
            float xv[8];
            *(float4*)&xv[0] = ar[cur][1][0]; *(float4*)&xv[4] = ar[cur][1][1];
            split3t(xv, af1);
        }
        // ---- 48 MFMAs: 8 independent chains (2m x 4ct), 6-deep, interleaved
        #pragma unroll
        for (int o = 0; o < 6; o++) {
            #pragma unroll
            for (int ct = 0; ct < 4; ct++) {
                acc[0][ct] = __builtin_amdgcn_mfma_f32_16x16x32_bf16(
                    af0[PA[o]], bfr[ct][PB[o]], acc[0][ct], 0, 0, 0);
                acc[1][ct] = __builtin_amdgcn_mfma_f32_16x16x32_bf16(
                    af1[PA[o]], bfr[ct][PB[o]], acc[1][ct], 0, 0, 0);
            }
        }
    }

    // ---- epilogue: C/D layout col=lane&15, row=quad*4+reg
    float g = 0.f, omg = 0.f;
    if (POST) { float sv = skipv[0]; g = 1.0f / (1.0f + expf(-sv)); omg = 1.0f - g; }
    #pragma unroll
    for (int m = 0; m < 2; m++) {
        #pragma unroll
        for (int ct = 0; ct < 4; ct++) {
            int col = bn + ct * 16 + l16;
            float bv = bias[col];
            #pragma unroll
            for (int i = 0; i < 4; i++) {
                int r = bm + wave * 32 + m * 16 + quad * 4 + i;
                if (r < M) {
                    float v = acc[m][ct][i] + bv;
                    if (POST) {
                        float rr = resid[(size_t)r * ldc + col];
                        v = fmaxf(g * v + omg * rr, 0.f);
                    }
                    C[(size_t)r * ldc + col] = v;
                }
            }
        }
    }
}

// ======================= fused attention gather (pipelined) ====================
// One wave per dst node, 16 lanes/edge, 4 edges in flight. Software pipeline:
// srcs prefetched 2 iterations ahead, k/v rows 1 iteration ahead -> the
// srcs->kv dependent-load chain is one-iteration-deep instead of serial.
// Math order identical to R8 (bit-identical output). Distributed gelu store.
__global__ __launch_bounds__(256)
void attn_gather(const int* __restrict__ row_ptr, const int* __restrict__ srcs,
                 float* __restrict__ qo, const float* __restrict__ kv,
                 const float* __restrict__ prel, int ndst)
{
    int wave = (blockIdx.x * 256 + threadIdx.x) >> 6;
    int lane = threadIdx.x & 63;
    if (wave >= ndst) return;
    int d = wave;
    int gl = lane & 15;
    int group = lane >> 4;
    int h = gl >> 2;
    float pr = prel[h] * 0.17677669529663687f;  // prel / sqrt(32)
    int beg = row_ptr[d], end = row_ptr[d + 1];
    const float* qrow = qo + (size_t)d * 128 + gl * 8;
    float4 q0 = *(const float4*)(qrow);
    float4 q1 = *(const float4*)(qrow + 4);
    const float* kvg = kv + gl * 8;
    float m = -1.0e30f, l = 0.f;
    float4 acc0 = make_float4(0.f,0.f,0.f,0.f), acc1 = acc0;
    int nt = (end - beg + 3) >> 2;

    // pipeline prologue: current (A) index+rows, next (B) index
    int iA = beg + group;
    int sA = (iA < end) ? srcs[iA] : -1;
    int iB = iA + 4;
    int sB = (iB < end) ? srcs[iB] : -1;
    float4 k0A, k1A, v0A, v1A;
    if (sA >= 0) {
        const float* row = kvg + (size_t)sA * 256;
        k0A = *(const float4*)(row);
        k1A = *(const float4*)(row + 4);
        v0A = *(const float4*)(row + 128);
        v1A = *(const float4*)(row + 132);
    }
    for (int t = 0; t < nt; t++) {
        // prefetch srcs index for t+2
        int iC = beg + (t + 2) * 4 + group;
        int sC = (iC < end) ? srcs[iC] : -1;
        // prefetch k/v rows for t+1
        float4 k0B, k1B, v0B, v1B;
        if (sB >= 0) {
            const float* row = kvg + (size_t)sB * 256;
            k0B = *(const float4*)(row);
            k1B = *(const float4*)(row + 4);
            v0B = *(const float4*)(row + 128);
            v1B = *(const float4*)(row + 132);
        }
        // compute iteration t (rows already in registers)
        if (sA >= 0) {
            float part = q0.x*k0A.x + q0.y*k0A.y + q0.z*k0A.z + q0.w*k0A.w
                       + q1.x*k1A.x + q1.y*k1A.y + q1.z*k1A.z + q1.w*k1A.w;
            part += __shfl_xor(part, 1);
            part += __shfl_xor(part, 2);
            float a = part * pr;
            float mn = fmaxf(m, a);
            float scale = __expf(m - mn);
            float p = __expf(a - mn);
            l = l * scale + p;
            acc0.x = acc0.x * scale + p * v0A.x;
            acc0.y = acc0.y * scale + p * v0A.y;
            acc0.z = acc0.z * scale + p * v0A.z;
            acc0.w = acc0.w * scale + p * v0A.w;
            acc1.x = acc1.x * scale + p * v1A.x;
            acc1.y = acc1.y * scale + p * v1A.y;
            acc1.z = acc1.z * scale + p * v1A.z;
            acc1.w = acc1.w * scale + p * v1A.w;
            m = mn;
        }
        // rotate pipeline
        sA = sB; sB = sC;
        k0A = k0B; k1A = k1B; v0A = v0B; v1A = v1B;
    }
    #pragma unroll
    for (int mask = 16; mask <= 32; mask <<= 1) {
        float m_o = __shfl_xor(m, mask);
        float l_o = __shfl_xor(l, mask);
        float4 a0o, a1o;
        a0o.x = __shfl_xor(acc0.x, mask); a0o.y = __shfl_xor(acc0.y, mask);
        a0o.z = __shfl_xor(acc0.z, mask); a0o.w = __shfl_xor(acc0.w, mask);
        a1o.x = __shfl_xor(acc1.x, mask); a1o.y = __shfl_xor(acc1.y, mask);
        a1o.z = __shfl_xor(acc1.z, mask); a1o.w = __shfl_xor(acc1.w, mask);
        float mn = fmaxf(m, m_o);
        float s0 = __expf(m - mn), s1 = __expf(m_o - mn);
        l = l * s0 + l_o * s1;
        acc0.x = acc0.x * s0 + a0o.x * s1; acc0.y = acc0.y * s0 + a0o.y * s1;
        acc0.z = acc0.z * s0 + a0o.z * s1; acc0.w = acc0.w * s0 + a0o.w * s1;
        acc1.x = acc1.x * s0 + a1o.x * s1; acc1.y = acc1.y * s0 + a1o.y * s1;
        acc1.z = acc1.z * s0 + a1o.z * s1; acc1.w = acc1.w * s0 + a1o.w * s1;
        m = mn;
    }
    float inv = (beg == end) ? 0.f : __builtin_amdgcn_rcpf(l + 1e-16f);
    // distributed gelu + store: group g handles floats [2g, 2g+2) of its column
    float s0v, s1v;
    if (group == 0)      { s0v = acc0.x; s1v = acc0.y; }
    else if (group == 1) { s0v = acc0.z; s1v = acc0.w; }
    else if (group == 2) { s0v = acc1.x; s1v = acc1.y; }
    else                 { s0v = acc1.z; s1v = acc1.w; }
    float2 o;
    o.x = gelu_f(s0v * inv);
    o.y = gelu_f(s1v * inv);
    *(float2*)(qo + (size_t)d * 128 + gl * 8 + group * 2) = o;
}

// ======================= final scoring =======================
__global__ __launch_bounds__(256)
void score_pairs(const int* __restrict__ ic, const int* __restrict__ id,
                 const float* __restrict__ zC, const float* __restrict__ zD,
                 float* __restrict__ out)
{
    int gid = blockIdx.x * 256 + threadIdx.x;
    int p = gid >> 4, lane = gid & 15;
    if (p >= L_CNT) return;
    int c = ic[p], d = id[p];
    float4 a = *(const float4*)(zC + (size_t)c * 64 + lane * 4);
    float4 b = *(const float4*)(zD + (size_t)d * 64 + lane * 4);
    float s = a.x * b.x + a.y * b.y + a.z * b.z + a.w * b.w;
    s += __shfl_down(s, 8, 16);
    s += __shfl_down(s, 4, 16);
    s += __shfl_down(s, 2, 16);
    s += __shfl_down(s, 1, 16);
    if (lane == 0) out[p] = fminf(10.0f, fmaxf(-10.0f, s));
}

extern "C" void kernel_launch(void* const* d_in, const int* in_sizes, int n_in,
                              void* d_out, int out_size, void* d_ws, size_t ws_size,
                              hipStream_t stream)
{
    float* xC = (float*)d_in[0];
    float* xD = (float*)d_in[1];
    const float* kW   = (const float*)d_in[2];
    const float* kb   = (const float*)d_in[3];
    const float* qW   = (const float*)d_in[4];
    const float* qb   = (const float*)d_in[5];
    const float* vW   = (const float*)d_in[6];
    const float* vb   = (const float*)d_in[7];
    const float* aW   = (const float*)d_in[8];
    const float* ab   = (const float*)d_in[9];
    const float* skip = (const float*)d_in[10];
    const float* arel = (const float*)d_in[11];
    const float* mrel = (const float*)d_in[12];
    const float* prel = (const float*)d_in[13];
    const float* outW = (const float*)d_in[14];
    const float* outb = (const float*)d_in[15];
    const int* ei_cd  = (const int*)d_in[16];
    const int* ei_dc  = (const int*)d_in[17];
    const int* eli    = (const int*)d_in[18];

    // ---- workspace ≈ 163 MB ----
    float* ws = (float*)d_ws;
    size_t off = 0;
    float* kv    = ws + off; off += (size_t)NN_ * 256;   // src [k|v]
    float* qo    = ws + off; off += (size_t)NN_ * 128;   // dst q -> gelu(attn out)
    float* Wcat  = ws + off; off += (size_t)4 * WCAT_SZ;
    unsigned short* WsCat = (unsigned short*)(ws + off); off += (4 * 3 * 384 * 128) / 2;
    unsigned short* aWs   = (unsigned short*)(ws + off); off += (4 * 3 * 128 * 128) / 2;
    unsigned short* outWs = (unsigned short*)(ws + off); off += (2 * 3 * 64 * 128) / 2;
    int* iws = (int*)(ws + off);
    size_t ioff = 0;
    int* rp      = iws + ioff; ioff += 2 * (NN_ + 1);
    int* srcsA   = iws + ioff; ioff += 2 * E_CNT;
    int* cnt     = iws + ioff; ioff += 2 * NN_;
    int* cursor  = iws + ioff; ioff += 2 * NN_;
    int* partial = iws + ioff; ioff += 256;
    float* zC = kv;
    float* zD = kv + (size_t)NN_ * 128;

    const int gridM = (NN_ + 255) / 256;          // 391 (256-row blocks)
    const int gE    = (E_CNT + 255) / 256;
    const int gN2   = (2 * NN_ + 255) / 256;
    const int gScan = 98;
    const int gGath = (NN_ + 3) / 4;

    // ---- CSR for both relations ----
    fill0_int<<<gN2, 256, 0, stream>>>(cnt, 2 * NN_);
    count_dst<<<dim3(gE, 2), 256, 0, stream>>>(ei_cd + E_CNT, ei_dc + E_CNT, cnt);
    scan_a<<<dim3(gScan, 2), 256, 0, stream>>>(cnt, rp, partial);
    scan_b<<<2, 128, 0, stream>>>(partial);
    scan_c<<<dim3(gScan, 2), 256, 0, stream>>>(rp, partial, cursor);
    scatter_edges<<<dim3(gE, 2), 256, 0, stream>>>(ei_cd, ei_cd + E_CNT,
                                                   ei_dc, ei_dc + E_CNT, cursor, srcsA);
    int* rp_cd   = rp;
    int* rp_dc   = rp + (NN_ + 1);
    int* srcs_cd = srcsA;
    int* srcs_dc = srcsA + E_CNT;

    // ---- weight fusion + bf16 3-term fragment-linear packs ----
    fuse_weights<<<dim3(129, 2, 2), 384, 0, stream>>>(qW, qb, kW, kb, vW, vb,
                                                      arel, mrel, Wcat);
    pack_w<<<dim3((384 * 16 + 255) / 256, 4), 256, 0, stream>>>(
        Wcat, 384, WCAT_SZ, WsCat, 384, 3 * 384 * 128);
    pack_w<<<dim3((128 * 16 + 255) / 256, 4), 256, 0, stream>>>(
        aW, 128, 128 * 128, aWs, 128, 3 * 128 * 128);
    pack_w<<<dim3((64 * 16 + 255) / 256, 2), 256, 0, stream>>>(
        outW, 64, 128 * 64, outWs, 64, 3 * 64 * 128);

    const int PS_CAT = 384 * 128;   // plane strides
    const int PS_AW  = 128 * 128;
    const int PS_OW  = 64 * 128;

    for (int l = 0; l < 2; l++) {
        const float* abl = ab + (size_t)l * 2 * 128;
        float* WcC = Wcat + (size_t)(l * 2 + 0) * WCAT_SZ;
        float* WcD = Wcat + (size_t)(l * 2 + 1) * WCAT_SZ;
        const unsigned short* WsC = WsCat + (size_t)(l * 2 + 0) * 3 * PS_CAT;
        const unsigned short* WsD = WsCat + (size_t)(l * 2 + 1) * 3 * PS_CAT;
        const unsigned short* aWsD = aWs + (size_t)(l * 2 + 1) * 3 * PS_AW;
        const unsigned short* aWsC = aWs + (size_t)(l * 2 + 0) * 3 * PS_AW;

        // ---- relation 0: C -> D ----  dual: y0-3 kvC (4 slabs), y4-5 qD (2 slabs)
        gemm_mfma<0><<<dim3(gridM, 6), 512, 0, stream>>>(
            xC, 128, WsC + 128 * 128, PS_CAT, WcC + 128 * 384 + 128, kv, 256, NC_,
            nullptr, nullptr,
            4, xD, WsD, PS_CAT, WcD + 128 * 384, qo, 128);
        attn_gather<<<gGath, 256, 0, stream>>>(rp_cd, srcs_cd, qo, kv,
                                               prel + (l * 2 + 0) * 4, ND_);

        // kvD from OLD xD (4 slabs)
        gemm_mfma<0><<<dim3(gridM, 4), 512, 0, stream>>>(
            xD, 128, WsD + 128 * 128, PS_CAT, WcD + 128 * 384 + 128, kv, 256, ND_,
            nullptr, nullptr, -1, nullptr, nullptr, 0, nullptr, nullptr, 0);

        // epilogue D (2 slabs)
        gemm_mfma<1><<<dim3(gridM, 2), 512, 0, stream>>>(
            qo, 128, aWsD, PS_AW, abl + 128, xD, 128, ND_,
            xD, skip + l * 2 + 1, -1, nullptr, nullptr, 0, nullptr, nullptr, 0);

        // ---- relation 1: D -> C ---- qC (2 slabs)
        gemm_mfma<0><<<dim3(gridM, 2), 512, 0, stream>>>(
            xC, 128, WsC, PS_CAT, WcC + 128 * 384, qo, 128, NC_,
            nullptr, nullptr, -1, nullptr, nullptr, 0, nullptr, nullptr, 0);
        attn_gather<<<gGath, 256, 0, stream>>>(rp_dc, srcs_dc, qo, kv,
                                               prel + (l * 2 + 1) * 4, NC_);

        // epilogue C (2 slabs)
        gemm_mfma<1><<<dim3(gridM, 2), 512, 0, stream>>>(
            qo, 128, aWsC, PS_AW, abl, xC, 128, NC_,
            xC, skip + l * 2 + 0, -1, nullptr, nullptr, 0, nullptr, nullptr, 0);
    }

    // final projections z = x @ outW + outb, both types dual (1 slab each)
    gemm_mfma<0><<<dim3(gridM, 2), 512, 0, stream>>>(
        xC, 128, outWs, PS_OW, outb, zC, 64, NC_, nullptr, nullptr,
        1, xD, outWs + 3 * PS_OW, PS_OW, outb + 64, zD, 64);

    score_pairs<<<(L_CNT * 16 + 255) / 256, 256, 0, stream>>>(
        eli, eli + L_CNT, zC, zD, (float*)d_out);
}